// Round 1
// baseline (6450.070 us; speedup 1.0000x reference)
//
#include <hip/hip_runtime.h>
#include <hip/hip_cooperative_groups.h>

namespace cg = cooperative_groups;

// Problem constants (fixed by the reference)
constexpr int Bb = 32;     // batch
constexpr int Tt = 32;     // time steps
constexpr int Ii = 8192;   // input dim
constexpr int Hh = 8192;   // hidden dim
constexpr int Oo = 2048;   // output dim

constexpr int RNN_BLOCKS  = 1024;  // 4 blocks/CU * 256 CU — safe cooperative co-residency
constexpr int RNN_THREADS = 256;
constexpr int RNN_WAVES   = RNN_BLOCKS * RNN_THREADS / 64;  // 4096 -> 2 rows/wave/step

// ---------------- x transpose: (B,T,I) -> (T,I,B) ----------------
__global__ void transpose_x_kernel(const float* __restrict__ x, float* __restrict__ xT) {
  // grid = Tt * (Ii/64) blocks, 256 threads
  int blk = blockIdx.x;
  int t  = blk >> 7;            // Ii/64 = 128
  int i0 = (blk & 127) << 6;
  __shared__ float lds[64][33]; // +1 pad: conflict-free both phases
  int tid = threadIdx.x;
  for (int idx = tid; idx < 32 * 64; idx += 256) {
    int bb = idx >> 6, il = idx & 63;  // coalesced 256B reads along i
    lds[il][bb] = x[(size_t)bb * Tt * Ii + (size_t)t * Ii + i0 + il];
  }
  __syncthreads();
  for (int idx = tid; idx < 64 * 32; idx += 256) {
    int il = idx >> 5, bb = idx & 31;  // fully contiguous 1KB writes
    xT[(size_t)t * Ii * Bb + (size_t)(i0 + il) * Bb + bb] = lds[il][bb];
  }
}

// ---------------- CSR build ----------------
__global__ void hist_kernel(const int* __restrict__ rows, int n, int* __restrict__ cnt) {
  int i = blockIdx.x * blockDim.x + threadIdx.x;
  int stride = gridDim.x * blockDim.x;
  for (; i < n; i += stride) atomicAdd(&cnt[rows[i]], 1);
}

// Single-block exclusive scan over cnt (n <= 8192). Writes row_start[0..n]
// and rewrites cnt in-place as the scatter cursor (= row starts).
__global__ void scan_kernel(int* __restrict__ cnt_cursor, int n, int* __restrict__ row_start) {
  __shared__ int sums[1024];
  int tid = threadIdx.x;
  int chunk = (n + 1023) >> 10;
  int base = tid * chunk;
  int s = 0;
  for (int i = 0; i < chunk; i++) {
    int idx = base + i;
    if (idx < n) s += cnt_cursor[idx];
  }
  sums[tid] = s;
  __syncthreads();
  for (int off = 1; off < 1024; off <<= 1) {   // Hillis-Steele inclusive scan
    int other = (tid >= off) ? sums[tid - off] : 0;
    __syncthreads();
    sums[tid] += other;
    __syncthreads();
  }
  int run = sums[tid] - s;  // exclusive prefix for this thread's chunk
  for (int i = 0; i < chunk; i++) {
    int idx = base + i;
    if (idx < n) {
      int v = cnt_cursor[idx];       // read before overwrite (thread-exclusive range)
      row_start[idx] = run;
      cnt_cursor[idx] = run;         // cursor init
      run += v;
    }
  }
  if (tid == 1023) row_start[n] = sums[1023];
}

__global__ void scatter_kernel(const int* __restrict__ rows, const int* __restrict__ cols,
                               const float* __restrict__ vals, int n,
                               int* __restrict__ cursor, int2* __restrict__ ent) {
  int i = blockIdx.x * blockDim.x + threadIdx.x;
  int stride = gridDim.x * blockDim.x;
  for (; i < n; i += stride) {
    int r = rows[i];
    int pos = atomicAdd(&cursor[r], 1);
    ent[pos] = make_int2(cols[i], __float_as_int(vals[i]));
  }
}

// ---------------- Recurrent loop (cooperative, 1 grid sync / step) ----------------
__global__ void __launch_bounds__(RNN_THREADS, 4) rnn_kernel(
    const int* __restrict__ ih_rs, const int2* __restrict__ ih_ent,
    const int* __restrict__ hh_rs, const int2* __restrict__ hh_ent,
    const float* __restrict__ hh_bias, const float* __restrict__ xT,
    float* __restrict__ hAll) {
  cg::grid_group grid = cg::this_grid();
  int gtid = blockIdx.x * blockDim.x + threadIdx.x;
  int wave = gtid >> 6;
  int lane = threadIdx.x & 63;
  int half = lane >> 5;   // half-wave handles alternate nnz
  int b    = lane & 31;   // batch lane -> 128B contiguous gathers

  for (int t = 0; t < Tt; t++) {
    const float* hprev = hAll + (size_t)t * Hh * Bb;       // slot 0 = zeros (h_{-1})
    const float* xt    = xT   + (size_t)t * Ii * Bb;
    float* hnext       = hAll + (size_t)(t + 1) * Hh * Bb;
    for (int r = wave; r < Hh; r += RNN_WAVES) {
      float acc0 = (half == 0) ? hh_bias[r] : 0.0f;
      float acc1 = 0.0f;
      // ih contribution
      int s0 = ih_rs[r], s1 = ih_rs[r + 1];
      int j = s0 + half;
      for (; j + 2 < s1; j += 4) {
        int2 e0 = ih_ent[j];
        int2 e1 = ih_ent[j + 2];
        acc0 += __int_as_float(e0.y) * xt[(size_t)e0.x * Bb + b];
        acc1 += __int_as_float(e1.y) * xt[(size_t)e1.x * Bb + b];
      }
      if (j < s1) {
        int2 e0 = ih_ent[j];
        acc0 += __int_as_float(e0.y) * xt[(size_t)e0.x * Bb + b];
      }
      // hh contribution
      s0 = hh_rs[r]; s1 = hh_rs[r + 1];
      j = s0 + half;
      for (; j + 2 < s1; j += 4) {
        int2 e0 = hh_ent[j];
        int2 e1 = hh_ent[j + 2];
        acc0 += __int_as_float(e0.y) * hprev[(size_t)e0.x * Bb + b];
        acc1 += __int_as_float(e1.y) * hprev[(size_t)e1.x * Bb + b];
      }
      if (j < s1) {
        int2 e0 = hh_ent[j];
        acc0 += __int_as_float(e0.y) * hprev[(size_t)e0.x * Bb + b];
      }
      float acc = acc0 + acc1;
      acc += __shfl_xor(acc, 32, 64);   // combine the two half-wave partials
      float hv = 1.0f / (1.0f + __expf(-acc));
      if (half == 0) hnext[(size_t)r * Bb + b] = hv;
    }
    grid.sync();
  }
}

// ---------------- Output spmm over all (t, o) rows ----------------
__global__ void out_kernel(const int* __restrict__ ho_rs, const int2* __restrict__ ho_ent,
                           const float* __restrict__ ho_bias, const float* __restrict__ hAll,
                           float* __restrict__ out_tmp) {
  int gtid = blockIdx.x * blockDim.x + threadIdx.x;
  int wave = gtid >> 6;
  int nwaves = (gridDim.x * blockDim.x) >> 6;
  int lane = threadIdx.x & 63;
  int half = lane >> 5, b = lane & 31;
  for (int p = wave; p < Tt * Oo; p += nwaves) {
    int t = p >> 11;          // Oo = 2048
    int r = p & (Oo - 1);
    const float* h = hAll + (size_t)(t + 1) * Hh * Bb;
    float acc0 = (half == 0) ? ho_bias[r] : 0.0f;
    float acc1 = 0.0f;
    int s0 = ho_rs[r], s1 = ho_rs[r + 1];
    int j = s0 + half;
    for (; j + 2 < s1; j += 4) {
      int2 e0 = ho_ent[j], e1 = ho_ent[j + 2];
      acc0 += __int_as_float(e0.y) * h[(size_t)e0.x * Bb + b];
      acc1 += __int_as_float(e1.y) * h[(size_t)e1.x * Bb + b];
    }
    if (j < s1) {
      int2 e = ho_ent[j];
      acc0 += __int_as_float(e.y) * h[(size_t)e.x * Bb + b];
    }
    float acc = acc0 + acc1;
    acc += __shfl_xor(acc, 32, 64);
    if (half == 0) out_tmp[(size_t)p * Bb + b] = acc;
  }
}

// ---------------- out transpose: (T,O,B) -> (B,T,O) ----------------
__global__ void transpose_out_kernel(const float* __restrict__ out_tmp, float* __restrict__ dout) {
  int blk = blockIdx.x;              // grid = Tt * (Oo/64) = 1024
  int t  = blk >> 5;                 // Oo/64 = 32
  int o0 = (blk & 31) << 6;
  __shared__ float lds[64][33];
  int tid = threadIdx.x;
  for (int idx = tid; idx < 64 * 32; idx += 256) {
    int ol = idx >> 5, bb = idx & 31;   // fully contiguous reads
    lds[ol][bb] = out_tmp[(size_t)t * Oo * Bb + (size_t)(o0 + ol) * Bb + bb];
  }
  __syncthreads();
  for (int idx = tid; idx < 32 * 64; idx += 256) {
    int bb = idx >> 6, ol = idx & 63;   // coalesced 256B writes per b
    dout[(size_t)bb * Tt * Oo + (size_t)t * Oo + o0 + ol] = lds[ol][bb];
  }
}

extern "C" void kernel_launch(void* const* d_in, const int* in_sizes, int n_in,
                              void* d_out, int out_size, void* d_ws, size_t ws_size,
                              hipStream_t stream) {
  const float* x       = (const float*)d_in[0];
  const int*   hh_rows = (const int*)d_in[1];
  const int*   hh_cols = (const int*)d_in[2];
  const float* hh_vals = (const float*)d_in[3];
  const float* hh_bias = (const float*)d_in[4];
  const int*   ih_rows = (const int*)d_in[5];
  const int*   ih_cols = (const int*)d_in[6];
  const float* ih_vals = (const float*)d_in[7];
  const int*   ho_rows = (const int*)d_in[8];
  const int*   ho_cols = (const int*)d_in[9];
  const float* ho_vals = (const float*)d_in[10];
  const float* ho_bias = (const float*)d_in[11];
  float* out = (float*)d_out;

  const int nnz_hh = in_sizes[1];
  const int nnz_ih = in_sizes[5];
  const int nnz_ho = in_sizes[8];

  // Workspace carve-up (~87 MB total)
  char* w = (char*)d_ws;
  size_t off = 0;
  auto alloc = [&](size_t bytes) -> void* {
    void* p = w + off;
    off += (bytes + 255) & ~(size_t)255;
    return p;
  };
  float* xT      = (float*)alloc(sizeof(float) * (size_t)Tt * Ii * Bb);        // 32 MB
  float* hAll    = (float*)alloc(sizeof(float) * (size_t)(Tt + 1) * Hh * Bb);  // 33 MB
  float* out_tmp = (float*)alloc(sizeof(float) * (size_t)Tt * Oo * Bb);        // 8 MB
  int*  ih_rs  = (int*)alloc(4 * (size_t)(Hh + 1));
  int*  ih_cur = (int*)alloc(4 * (size_t)Hh);
  int2* ih_ent = (int2*)alloc(8 * (size_t)nnz_ih);                             // 4 MB
  int*  hh_rs  = (int*)alloc(4 * (size_t)(Hh + 1));
  int*  hh_cur = (int*)alloc(4 * (size_t)Hh);
  int2* hh_ent = (int2*)alloc(8 * (size_t)nnz_hh);                             // 8 MB
  int*  ho_rs  = (int*)alloc(4 * (size_t)(Oo + 1));
  int*  ho_cur = (int*)alloc(4 * (size_t)Oo);
  int2* ho_ent = (int2*)alloc(8 * (size_t)nnz_ho);                             // 2 MB

  // Init: zero h_{-1} slot and the histogram/cursor arrays
  hipMemsetAsync(hAll, 0, sizeof(float) * (size_t)Hh * Bb, stream);
  hipMemsetAsync(ih_cur, 0, 4 * (size_t)Hh, stream);
  hipMemsetAsync(hh_cur, 0, 4 * (size_t)Hh, stream);
  hipMemsetAsync(ho_cur, 0, 4 * (size_t)Oo, stream);

  // x transpose
  transpose_x_kernel<<<Tt * (Ii / 64), 256, 0, stream>>>(x, xT);

  // CSR build: histogram -> scan -> scatter
  hist_kernel<<<1024, 256, 0, stream>>>(ih_rows, nnz_ih, ih_cur);
  hist_kernel<<<1024, 256, 0, stream>>>(hh_rows, nnz_hh, hh_cur);
  hist_kernel<<<1024, 256, 0, stream>>>(ho_rows, nnz_ho, ho_cur);
  scan_kernel<<<1, 1024, 0, stream>>>(ih_cur, Hh, ih_rs);
  scan_kernel<<<1, 1024, 0, stream>>>(hh_cur, Hh, hh_rs);
  scan_kernel<<<1, 1024, 0, stream>>>(ho_cur, Oo, ho_rs);
  scatter_kernel<<<1024, 256, 0, stream>>>(ih_rows, ih_cols, ih_vals, nnz_ih, ih_cur, ih_ent);
  scatter_kernel<<<1024, 256, 0, stream>>>(hh_rows, hh_cols, hh_vals, nnz_hh, hh_cur, hh_ent);
  scatter_kernel<<<1024, 256, 0, stream>>>(ho_rows, ho_cols, ho_vals, nnz_ho, ho_cur, ho_ent);

  // Recurrence: cooperative launch, grid.sync() between steps
  {
    void* args[] = {(void*)&ih_rs, (void*)&ih_ent, (void*)&hh_rs, (void*)&hh_ent,
                    (void*)&hh_bias, (void*)&xT, (void*)&hAll};
    hipLaunchCooperativeKernel((const void*)rnn_kernel, dim3(RNN_BLOCKS), dim3(RNN_THREADS),
                               args, 0, stream);
  }

  // Output spmm over all (t, o) rows, then transpose to (B,T,O)
  out_kernel<<<2048, 256, 0, stream>>>(ho_rs, ho_ent, ho_bias, hAll, out_tmp);
  transpose_out_kernel<<<Tt * (Oo / 64), 256, 0, stream>>>(out_tmp, out);

  (void)n_in; (void)out_size; (void)ws_size;
}

// Round 2
// 5295.192 us; speedup vs baseline: 1.2181x; 1.2181x over previous
//
#include <hip/hip_runtime.h>
#include <hip/hip_cooperative_groups.h>

namespace cg = cooperative_groups;

// Problem constants (fixed by the reference)
constexpr int Bb = 32;     // batch
constexpr int Tt = 32;     // time steps
constexpr int Ii = 8192;   // input dim
constexpr int Hh = 8192;   // hidden dim
constexpr int Oo = 2048;   // output dim

constexpr int RNN_BLOCKS = 1024;
constexpr int CAP = 256;   // staged entries per row slot (max row nnz ~175 for Poisson(128))

// ---------------- x transpose: (B,T,I) -> (I,T,B) ----------------
// x2[i*1024 + t*32 + b] = x[b*T*I + t*I + i]
__global__ void transpose_x_kernel(const float* __restrict__ x, float* __restrict__ x2) {
  // grid = (Tt/2) * (Ii/64) = 2048 blocks, 256 threads
  int blk = blockIdx.x;
  int tp = blk >> 7;             // Ii/64 = 128
  int ib = blk & 127;
  int t0 = tp * 2;
  int i0 = ib * 64;
  __shared__ float lds[64][65];  // [il][tt*32+b], pad -> conflict-free both phases
  int tid = threadIdx.x;
  for (int idx = tid; idx < 64 * 64; idx += 256) {
    int row = idx >> 6;          // tt*32 + b
    int il  = idx & 63;          // coalesced 256B reads along i
    int tt = row >> 5, bb = row & 31;
    lds[il][row] = x[(size_t)bb * Tt * Ii + (size_t)(t0 + tt) * Ii + i0 + il];
  }
  __syncthreads();
  for (int idx = tid; idx < 64 * 64; idx += 256) {
    int il = idx >> 6;
    int row = idx & 63;          // contiguous 256B writes
    x2[(size_t)(i0 + il) * (Tt * Bb) + t0 * Bb + row] = lds[il][row];
  }
}

// ---------------- CSR build ----------------
__global__ void hist_kernel(const int* __restrict__ rows, int n, int* __restrict__ cnt) {
  int i = blockIdx.x * blockDim.x + threadIdx.x;
  int stride = gridDim.x * blockDim.x;
  for (; i < n; i += stride) atomicAdd(&cnt[rows[i]], 1);
}

__global__ void scan_kernel(int* __restrict__ cnt_cursor, int n, int* __restrict__ row_start) {
  __shared__ int sums[1024];
  int tid = threadIdx.x;
  int chunk = (n + 1023) >> 10;
  int base = tid * chunk;
  int s = 0;
  for (int i = 0; i < chunk; i++) {
    int idx = base + i;
    if (idx < n) s += cnt_cursor[idx];
  }
  sums[tid] = s;
  __syncthreads();
  for (int off = 1; off < 1024; off <<= 1) {
    int other = (tid >= off) ? sums[tid - off] : 0;
    __syncthreads();
    sums[tid] += other;
    __syncthreads();
  }
  int run = sums[tid] - s;
  for (int i = 0; i < chunk; i++) {
    int idx = base + i;
    if (idx < n) {
      int v = cnt_cursor[idx];
      row_start[idx] = run;
      cnt_cursor[idx] = run;
      run += v;
    }
  }
  if (tid == 1023) row_start[n] = sums[1023];
}

__global__ void scatter_kernel(const int* __restrict__ rows, const int* __restrict__ cols,
                               const float* __restrict__ vals, int n,
                               int* __restrict__ cursor, int2* __restrict__ ent) {
  int i = blockIdx.x * blockDim.x + threadIdx.x;
  int stride = gridDim.x * blockDim.x;
  for (; i < n; i += stride) {
    int r = rows[i];
    int pos = atomicAdd(&cursor[r], 1);
    ent[pos] = make_int2(cols[i], __float_as_int(vals[i]));
  }
}

// ---------------- preIH: pre[t][r][b] = bias[r] + sum_ih (all t, fully parallel) ----------------
__global__ void __launch_bounds__(256, 4) preih_kernel(
    const int* __restrict__ ih_rs, const int2* __restrict__ ih_ent,
    const float* __restrict__ hh_bias, const float* __restrict__ x2,
    float* __restrict__ preAll) {
  int gtid = blockIdx.x * blockDim.x + threadIdx.x;
  int r = gtid >> 6;            // wave per row; grid gives exactly 8192 waves
  if (r >= Hh) return;
  int lane = threadIdx.x & 63;
  float bias = hh_bias[r];
  float acc[16];
#pragma unroll
  for (int k = 0; k < 16; k++) acc[k] = 0.0f;
  int s0 = ih_rs[r], s1 = ih_rs[r + 1];
  int j = s0;
  for (; j + 2 <= s1; j += 2) {
    int2 e0 = ih_ent[j];
    int2 e1 = ih_ent[j + 1];
    const float* p0 = x2 + (size_t)e0.x * (Tt * Bb);
    const float* p1 = x2 + (size_t)e1.x * (Tt * Bb);
    float v0 = __int_as_float(e0.y), v1 = __int_as_float(e1.y);
#pragma unroll
    for (int k = 0; k < 16; k++) {
      acc[k] += v0 * p0[k * 64 + lane];   // lane covers t=2k+h, b
      acc[k] += v1 * p1[k * 64 + lane];
    }
  }
  if (j < s1) {
    int2 e = ih_ent[j];
    const float* p0 = x2 + (size_t)e.x * (Tt * Bb);
    float v = __int_as_float(e.y);
#pragma unroll
    for (int k = 0; k < 16; k++) acc[k] += v * p0[k * 64 + lane];
  }
  int h = lane >> 5, b = lane & 31;
#pragma unroll
  for (int k = 0; k < 16; k++) {
    int t = 2 * k + h;
    preAll[((size_t)t * Hh + r) * Bb + b] = acc[k] + bias;
  }
}

// ---------------- Recurrence (cooperative, LDS-staged entries, 1 sync/step) ----------------
__global__ void __launch_bounds__(512, 8) rnn_kernel(
    const int* __restrict__ hh_rs, const int2* __restrict__ hh_ent,
    const float* __restrict__ preAll, float* __restrict__ hAll, int nwaves) {
  cg::grid_group grid = cg::this_grid();
  __shared__ int2 lent[8][2][CAP];   // 32 KB: [wave-in-block][row slot][entry]
  int gtid = blockIdx.x * blockDim.x + threadIdx.x;
  int wave = gtid >> 6;
  int wib  = threadIdx.x >> 6;
  int lane = threadIdx.x & 63;
  int h = lane >> 5, b = lane & 31;

  // Stage this wave's row entries into LDS once (rows are step-invariant)
  int s0s[2], cnts[2];
  {
    int slot = 0;
    for (int r = wave; r < Hh; r += nwaves, slot++) {
      int s0 = hh_rs[r], s1 = hh_rs[r + 1];
      s0s[slot] = s0;
      cnts[slot] = s1 - s0;
      int cs = min(s1 - s0, CAP);
      for (int m = lane; m < cs; m += 64) lent[wib][slot][m] = hh_ent[s0 + m];
    }
  }
  __syncthreads();

  for (int t = 0; t < Tt; t++) {
    const float* hprev = hAll + (size_t)t * (Hh * Bb);     // slot 0 = zeros
    float* hnext       = hAll + (size_t)(t + 1) * (Hh * Bb);
    const float* pre_t = preAll + (size_t)t * (Hh * Bb);
    int sl = 0;
    for (int r = wave; r < Hh; r += nwaves, sl++) {
      int cnt = cnts[sl];
      int cs = min(cnt, CAP);
      const int2* le = lent[wib][sl];
      float pre = pre_t[r * Bb + b];
      float a0 = 0.f, a1 = 0.f, a2 = 0.f, a3 = 0.f;
      int nh = (cs - h + 1) >> 1;       // entries of parity h below cs
      int m = 0;
      for (; m + 4 <= nh; m += 4) {
        int p = h + 2 * m;
        int2 e0 = le[p];
        int2 e1 = le[p + 2];
        int2 e2 = le[p + 4];
        int2 e3 = le[p + 6];
        a0 += __int_as_float(e0.y) * hprev[e0.x * Bb + b];
        a1 += __int_as_float(e1.y) * hprev[e1.x * Bb + b];
        a2 += __int_as_float(e2.y) * hprev[e2.x * Bb + b];
        a3 += __int_as_float(e3.y) * hprev[e3.x * Bb + b];
      }
      for (; m < nh; m++) {
        int2 e = le[h + 2 * m];
        a0 += __int_as_float(e.y) * hprev[e.x * Bb + b];
      }
      // overflow beyond CAP (essentially never; CAP even keeps parity)
      for (int p = cs + h; p < cnt; p += 2) {
        int2 e = hh_ent[s0s[sl] + p];
        a0 += __int_as_float(e.y) * hprev[e.x * Bb + b];
      }
      float acc = (a0 + a1) + (a2 + a3);
      acc += __shfl_xor(acc, 32, 64);
      float hv = 1.0f / (1.0f + __expf(-(pre + acc)));
      if (h == 0) hnext[r * Bb + b] = hv;
    }
    grid.sync();
  }
}

// ---------------- Output spmm over all (t, o) rows ----------------
__global__ void out_kernel(const int* __restrict__ ho_rs, const int2* __restrict__ ho_ent,
                           const float* __restrict__ ho_bias, const float* __restrict__ hAll,
                           float* __restrict__ out_tmp) {
  int gtid = blockIdx.x * blockDim.x + threadIdx.x;
  int wave = gtid >> 6;
  int nwaves = (gridDim.x * blockDim.x) >> 6;
  int lane = threadIdx.x & 63;
  int half = lane >> 5, b = lane & 31;
  for (int p = wave; p < Tt * Oo; p += nwaves) {
    int t = p >> 11;          // Oo = 2048
    int r = p & (Oo - 1);
    const float* hcur = hAll + (size_t)(t + 1) * (Hh * Bb);
    float a0 = (half == 0) ? ho_bias[r] : 0.0f;
    float a1 = 0.f, a2 = 0.f, a3 = 0.f;
    int s0 = ho_rs[r], s1 = ho_rs[r + 1];
    int nh = (s1 - s0 - half + 1) >> 1;
    int m = 0;
    for (; m + 4 <= nh; m += 4) {
      int p0 = s0 + half + 2 * m;
      int2 e0 = ho_ent[p0];
      int2 e1 = ho_ent[p0 + 2];
      int2 e2 = ho_ent[p0 + 4];
      int2 e3 = ho_ent[p0 + 6];
      a0 += __int_as_float(e0.y) * hcur[e0.x * Bb + b];
      a1 += __int_as_float(e1.y) * hcur[e1.x * Bb + b];
      a2 += __int_as_float(e2.y) * hcur[e2.x * Bb + b];
      a3 += __int_as_float(e3.y) * hcur[e3.x * Bb + b];
    }
    for (; m < nh; m++) {
      int2 e = ho_ent[s0 + half + 2 * m];
      a0 += __int_as_float(e.y) * hcur[e.x * Bb + b];
    }
    float acc = (a0 + a1) + (a2 + a3);
    acc += __shfl_xor(acc, 32, 64);
    if (half == 0) out_tmp[(size_t)p * Bb + b] = acc;
  }
}

// ---------------- out transpose: (T,O,B) -> (B,T,O) ----------------
__global__ void transpose_out_kernel(const float* __restrict__ out_tmp, float* __restrict__ dout) {
  int blk = blockIdx.x;              // grid = Tt * (Oo/64) = 1024
  int t  = blk >> 5;                 // Oo/64 = 32
  int o0 = (blk & 31) << 6;
  __shared__ float lds[64][33];
  int tid = threadIdx.x;
  for (int idx = tid; idx < 64 * 32; idx += 256) {
    int ol = idx >> 5, bb = idx & 31;   // fully contiguous reads
    lds[ol][bb] = out_tmp[(size_t)t * Oo * Bb + (size_t)(o0 + ol) * Bb + bb];
  }
  __syncthreads();
  for (int idx = tid; idx < 32 * 64; idx += 256) {
    int bb = idx >> 6, ol = idx & 63;   // coalesced 256B writes per b
    dout[(size_t)bb * Tt * Oo + (size_t)t * Oo + o0 + ol] = lds[ol][bb];
  }
}

extern "C" void kernel_launch(void* const* d_in, const int* in_sizes, int n_in,
                              void* d_out, int out_size, void* d_ws, size_t ws_size,
                              hipStream_t stream) {
  const float* x       = (const float*)d_in[0];
  const int*   hh_rows = (const int*)d_in[1];
  const int*   hh_cols = (const int*)d_in[2];
  const float* hh_vals = (const float*)d_in[3];
  const float* hh_bias = (const float*)d_in[4];
  const int*   ih_rows = (const int*)d_in[5];
  const int*   ih_cols = (const int*)d_in[6];
  const float* ih_vals = (const float*)d_in[7];
  const int*   ho_rows = (const int*)d_in[8];
  const int*   ho_cols = (const int*)d_in[9];
  const float* ho_vals = (const float*)d_in[10];
  const float* ho_bias = (const float*)d_in[11];
  float* out = (float*)d_out;

  const int nnz_hh = in_sizes[1];
  const int nnz_ih = in_sizes[5];
  const int nnz_ho = in_sizes[8];

  // Workspace carve-up (~111 MB; out_tmp aliases x2 which is dead after preih)
  char* w = (char*)d_ws;
  size_t off = 0;
  auto alloc = [&](size_t bytes) -> void* {
    void* p = w + off;
    off += (bytes + 255) & ~(size_t)255;
    return p;
  };
  float* x2      = (float*)alloc(sizeof(float) * (size_t)Ii * Tt * Bb);        // 32 MB
  float* hAll    = (float*)alloc(sizeof(float) * (size_t)(Tt + 1) * Hh * Bb);  // 33 MB
  float* preAll  = (float*)alloc(sizeof(float) * (size_t)Tt * Hh * Bb);        // 32 MB
  int*  ih_rs  = (int*)alloc(4 * (size_t)(Hh + 1));
  int*  ih_cur = (int*)alloc(4 * (size_t)Hh);
  int2* ih_ent = (int2*)alloc(8 * (size_t)nnz_ih);                             // 4 MB
  int*  hh_rs  = (int*)alloc(4 * (size_t)(Hh + 1));
  int*  hh_cur = (int*)alloc(4 * (size_t)Hh);
  int2* hh_ent = (int2*)alloc(8 * (size_t)nnz_hh);                             // 8 MB
  int*  ho_rs  = (int*)alloc(4 * (size_t)(Oo + 1));
  int*  ho_cur = (int*)alloc(4 * (size_t)Oo);
  int2* ho_ent = (int2*)alloc(8 * (size_t)nnz_ho);                             // 2 MB
  float* out_tmp = x2;   // alias: x2 dead after preih_kernel

  // Init
  hipMemsetAsync(hAll, 0, sizeof(float) * (size_t)Hh * Bb, stream);
  hipMemsetAsync(ih_cur, 0, 4 * (size_t)Hh, stream);
  hipMemsetAsync(hh_cur, 0, 4 * (size_t)Hh, stream);
  hipMemsetAsync(ho_cur, 0, 4 * (size_t)Oo, stream);

  // x -> (I,T,B)
  transpose_x_kernel<<<(Tt / 2) * (Ii / 64), 256, 0, stream>>>(x, x2);

  // CSR build
  hist_kernel<<<1024, 256, 0, stream>>>(ih_rows, nnz_ih, ih_cur);
  hist_kernel<<<1024, 256, 0, stream>>>(hh_rows, nnz_hh, hh_cur);
  hist_kernel<<<1024, 256, 0, stream>>>(ho_rows, nnz_ho, ho_cur);
  scan_kernel<<<1, 1024, 0, stream>>>(ih_cur, Hh, ih_rs);
  scan_kernel<<<1, 1024, 0, stream>>>(hh_cur, Hh, hh_rs);
  scan_kernel<<<1, 1024, 0, stream>>>(ho_cur, Oo, ho_rs);
  scatter_kernel<<<1024, 256, 0, stream>>>(ih_rows, ih_cols, ih_vals, nnz_ih, ih_cur, ih_ent);
  scatter_kernel<<<1024, 256, 0, stream>>>(hh_rows, hh_cols, hh_vals, nnz_hh, hh_cur, hh_ent);
  scatter_kernel<<<1024, 256, 0, stream>>>(ho_rows, ho_cols, ho_vals, nnz_ho, ho_cur, ho_ent);

  // pre[t][r][b] for all t (fully parallel)
  preih_kernel<<<2048, 256, 0, stream>>>(ih_rs, ih_ent, hh_bias, x2, preAll);

  // Recurrence: prefer 512 threads (1 row/wave, full occupancy); fall back if it won't co-reside
  int threads = 512;
  int maxB = 0;
  if (hipOccupancyMaxActiveBlocksPerMultiprocessor(&maxB, rnn_kernel, 512, 0) != hipSuccess ||
      maxB < 4) {
    threads = 256;
  }
  int nwaves = RNN_BLOCKS * threads / 64;
  {
    void* args[] = {(void*)&hh_rs, (void*)&hh_ent, (void*)&preAll, (void*)&hAll, (void*)&nwaves};
    hipLaunchCooperativeKernel((const void*)rnn_kernel, dim3(RNN_BLOCKS), dim3(threads),
                               args, 0, stream);
  }

  // Output spmm + final transpose
  out_kernel<<<2048, 256, 0, stream>>>(ho_rs, ho_ent, ho_bias, hAll, out_tmp);
  transpose_out_kernel<<<Tt * (Oo / 64), 256, 0, stream>>>(out_tmp, out);

  (void)n_in; (void)out_size; (void)ws_size;
}

// Round 3
// 1357.436 us; speedup vs baseline: 4.7517x; 3.9009x over previous
//
#include <hip/hip_runtime.h>

// Problem constants (fixed by the reference)
constexpr int Bb = 32;     // batch
constexpr int Tt = 32;     // time steps
constexpr int Ii = 8192;   // input dim
constexpr int Hh = 8192;   // hidden dim
constexpr int Oo = 2048;   // output dim

// ---------------- x transpose: (B,T,I) -> (I,T,B) ----------------
__global__ void transpose_x_kernel(const float* __restrict__ x, float* __restrict__ x2) {
  // grid = (Tt/2) * (Ii/64) = 2048 blocks, 256 threads
  int blk = blockIdx.x;
  int tp = blk >> 7;             // Ii/64 = 128
  int ib = blk & 127;
  int t0 = tp * 2;
  int i0 = ib * 64;
  __shared__ float lds[64][65];
  int tid = threadIdx.x;
  for (int idx = tid; idx < 64 * 64; idx += 256) {
    int row = idx >> 6;          // tt*32 + b
    int il  = idx & 63;          // coalesced reads along i
    int tt = row >> 5, bb = row & 31;
    lds[il][row] = x[(size_t)bb * Tt * Ii + (size_t)(t0 + tt) * Ii + i0 + il];
  }
  __syncthreads();
  for (int idx = tid; idx < 64 * 64; idx += 256) {
    int il = idx >> 6;
    int row = idx & 63;          // contiguous writes
    x2[(size_t)(i0 + il) * (Tt * Bb) + t0 * Bb + row] = lds[il][row];
  }
}

// ---------------- CSR build ----------------
__global__ void hist_kernel(const int* __restrict__ rows, int n, int* __restrict__ cnt) {
  int i = blockIdx.x * blockDim.x + threadIdx.x;
  int stride = gridDim.x * blockDim.x;
  for (; i < n; i += stride) atomicAdd(&cnt[rows[i]], 1);
}

// Exclusive scan over counts; pad!=0 rounds each row's count up to even so
// every row start is 16B-aligned in the int2 entry array (for int4 pair loads).
__global__ void scan_kernel(int* __restrict__ cnt_cursor, int n, int* __restrict__ row_start,
                            int pad) {
  __shared__ int sums[1024];
  int tid = threadIdx.x;
  int chunk = (n + 1023) >> 10;
  int base = tid * chunk;
  int s = 0;
  for (int i = 0; i < chunk; i++) {
    int idx = base + i;
    if (idx < n) {
      int v = cnt_cursor[idx];
      s += pad ? ((v + 1) & ~1) : v;
    }
  }
  sums[tid] = s;
  __syncthreads();
  for (int off = 1; off < 1024; off <<= 1) {
    int other = (tid >= off) ? sums[tid - off] : 0;
    __syncthreads();
    sums[tid] += other;
    __syncthreads();
  }
  int run = sums[tid] - s;
  for (int i = 0; i < chunk; i++) {
    int idx = base + i;
    if (idx < n) {
      int v = cnt_cursor[idx];
      row_start[idx] = run;
      cnt_cursor[idx] = run;
      run += pad ? ((v + 1) & ~1) : v;
    }
  }
  if (tid == 1023) row_start[n] = sums[1023];
}

__global__ void scatter_kernel(const int* __restrict__ rows, const int* __restrict__ cols,
                               const float* __restrict__ vals, int n,
                               int* __restrict__ cursor, int2* __restrict__ ent) {
  int i = blockIdx.x * blockDim.x + threadIdx.x;
  int stride = gridDim.x * blockDim.x;
  for (; i < n; i += stride) {
    int r = rows[i];
    int pos = atomicAdd(&cursor[r], 1);
    ent[pos] = make_int2(cols[i], __float_as_int(vals[i]));
  }
}

// ---------------- preIH: pre[t][r][b] = bias[r] + sum_ih (all t, fully parallel) ----------------
__global__ void __launch_bounds__(256, 4) preih_kernel(
    const int* __restrict__ ih_rs, const int2* __restrict__ ih_ent,
    const float* __restrict__ hh_bias, const float* __restrict__ x2,
    float* __restrict__ preAll) {
  int gtid = blockIdx.x * blockDim.x + threadIdx.x;
  int r = gtid >> 6;            // wave per row; grid gives exactly 8192 waves
  if (r >= Hh) return;
  int lane = threadIdx.x & 63;
  float bias = hh_bias[r];
  float acc[16];
#pragma unroll
  for (int k = 0; k < 16; k++) acc[k] = 0.0f;
  int s0 = ih_rs[r], s1 = ih_rs[r + 1];
  int j = s0;
  for (; j + 2 <= s1; j += 2) {
    int2 e0 = ih_ent[j];
    int2 e1 = ih_ent[j + 1];
    const float* p0 = x2 + (size_t)e0.x * (Tt * Bb);
    const float* p1 = x2 + (size_t)e1.x * (Tt * Bb);
    float v0 = __int_as_float(e0.y), v1 = __int_as_float(e1.y);
#pragma unroll
    for (int k = 0; k < 16; k++) {
      acc[k] += v0 * p0[k * 64 + lane];
      acc[k] += v1 * p1[k * 64 + lane];
    }
  }
  if (j < s1) {
    int2 e = ih_ent[j];
    const float* p0 = x2 + (size_t)e.x * (Tt * Bb);
    float v = __int_as_float(e.y);
#pragma unroll
    for (int k = 0; k < 16; k++) acc[k] += v * p0[k * 64 + lane];
  }
  int h = lane >> 5, b = lane & 31;
#pragma unroll
  for (int k = 0; k < 16; k++) {
    int t = 2 * k + h;
    preAll[((size_t)t * Hh + r) * Bb + b] = acc[k] + bias;
  }
}

// ---------------- One recurrence step: h_{t+1} = sigmoid(pre_t + HH @ h_t) ----------------
// Grid: 2048 blocks x 256 threads = 8192 waves = one wave per row.
// Entries stored as zero-padded int4 pairs (row starts even). Half-wave h
// processes entries of parity h; lanes cover batch. VGPR<=64 via launch_bounds
// so all 8192 waves co-reside in a single pass.
__global__ void __launch_bounds__(256, 8) step_kernel(
    const int* __restrict__ hh_rs, const int* __restrict__ hh_cur,
    const int4* __restrict__ hh_entp,
    const float* __restrict__ pre_t,
    const float* __restrict__ hprev,
    float* __restrict__ hnext) {
  int wave = (blockIdx.x * 256 + threadIdx.x) >> 6;   // == row r, exactly Hh waves
  int lane = threadIdx.x & 63;
  int h = lane >> 5, b = lane & 31;
  int r = wave;
  int s0  = __builtin_amdgcn_readfirstlane(hh_rs[r]);      // even
  int cnt = __builtin_amdgcn_readfirstlane(hh_cur[r]) - s0; // scatter cursor ended at s0+cnt
  int np = (cnt + 1) >> 1;                                  // pairs (pad pair-half is zeroed)
  const int4* ep = hh_entp + (s0 >> 1);
  float pre = pre_t[r * Bb + b];

  float a0 = 0.f, a1 = 0.f, a2 = 0.f, a3 = 0.f;
  int m = 0;
  for (; m + 4 <= np; m += 4) {
    int4 e0 = ep[m];
    int4 e1 = ep[m + 1];
    int4 e2 = ep[m + 2];
    int4 e3 = ep[m + 3];
    int   c0 = h ? e0.z : e0.x;  float v0 = __int_as_float(h ? e0.w : e0.y);
    int   c1 = h ? e1.z : e1.x;  float v1 = __int_as_float(h ? e1.w : e1.y);
    int   c2 = h ? e2.z : e2.x;  float v2 = __int_as_float(h ? e2.w : e2.y);
    int   c3 = h ? e3.z : e3.x;  float v3 = __int_as_float(h ? e3.w : e3.y);
    a0 += v0 * hprev[(c0 << 5) + b];
    a1 += v1 * hprev[(c1 << 5) + b];
    a2 += v2 * hprev[(c2 << 5) + b];
    a3 += v3 * hprev[(c3 << 5) + b];
  }
  for (; m < np; m++) {
    int4 e = ep[m];
    int   c = h ? e.z : e.x;  float v = __int_as_float(h ? e.w : e.y);
    a0 += v * hprev[(c << 5) + b];
  }
  float acc = (a0 + a1) + (a2 + a3);
  acc += __shfl_xor(acc, 32, 64);       // combine the two parity halves
  float hv = 1.0f / (1.0f + __expf(-(pre + acc)));
  if (h == 0) hnext[(r << 5) + b] = hv;
}

// ---------------- Output spmm over all (t, o) rows ----------------
__global__ void out_kernel(const int* __restrict__ ho_rs, const int2* __restrict__ ho_ent,
                           const float* __restrict__ ho_bias, const float* __restrict__ hAll,
                           float* __restrict__ out_tmp) {
  int gtid = blockIdx.x * blockDim.x + threadIdx.x;
  int wave = gtid >> 6;
  int nwaves = (gridDim.x * blockDim.x) >> 6;
  int lane = threadIdx.x & 63;
  int half = lane >> 5, b = lane & 31;
  for (int p = wave; p < Tt * Oo; p += nwaves) {
    int t = p >> 11;          // Oo = 2048
    int r = p & (Oo - 1);
    const float* hcur = hAll + (size_t)(t + 1) * (Hh * Bb);
    float a0 = (half == 0) ? ho_bias[r] : 0.0f;
    float a1 = 0.f, a2 = 0.f, a3 = 0.f;
    int s0 = ho_rs[r], s1 = ho_rs[r + 1];
    int nh = (s1 - s0 - half + 1) >> 1;
    int m = 0;
    for (; m + 4 <= nh; m += 4) {
      int p0 = s0 + half + 2 * m;
      int2 e0 = ho_ent[p0];
      int2 e1 = ho_ent[p0 + 2];
      int2 e2 = ho_ent[p0 + 4];
      int2 e3 = ho_ent[p0 + 6];
      a0 += __int_as_float(e0.y) * hcur[e0.x * Bb + b];
      a1 += __int_as_float(e1.y) * hcur[e1.x * Bb + b];
      a2 += __int_as_float(e2.y) * hcur[e2.x * Bb + b];
      a3 += __int_as_float(e3.y) * hcur[e3.x * Bb + b];
    }
    for (; m < nh; m++) {
      int2 e = ho_ent[s0 + half + 2 * m];
      a0 += __int_as_float(e.y) * hcur[e.x * Bb + b];
    }
    float acc = (a0 + a1) + (a2 + a3);
    acc += __shfl_xor(acc, 32, 64);
    if (half == 0) out_tmp[(size_t)p * Bb + b] = acc;
  }
}

// ---------------- out transpose: (T,O,B) -> (B,T,O) ----------------
__global__ void transpose_out_kernel(const float* __restrict__ out_tmp, float* __restrict__ dout) {
  int blk = blockIdx.x;              // grid = Tt * (Oo/64) = 1024
  int t  = blk >> 5;
  int o0 = (blk & 31) << 6;
  __shared__ float lds[64][33];
  int tid = threadIdx.x;
  for (int idx = tid; idx < 64 * 32; idx += 256) {
    int ol = idx >> 5, bb = idx & 31;
    lds[ol][bb] = out_tmp[(size_t)t * Oo * Bb + (size_t)(o0 + ol) * Bb + bb];
  }
  __syncthreads();
  for (int idx = tid; idx < 32 * 64; idx += 256) {
    int bb = idx >> 6, ol = idx & 63;
    dout[(size_t)bb * Tt * Oo + (size_t)t * Oo + o0 + ol] = lds[ol][bb];
  }
}

extern "C" void kernel_launch(void* const* d_in, const int* in_sizes, int n_in,
                              void* d_out, int out_size, void* d_ws, size_t ws_size,
                              hipStream_t stream) {
  const float* x       = (const float*)d_in[0];
  const int*   hh_rows = (const int*)d_in[1];
  const int*   hh_cols = (const int*)d_in[2];
  const float* hh_vals = (const float*)d_in[3];
  const float* hh_bias = (const float*)d_in[4];
  const int*   ih_rows = (const int*)d_in[5];
  const int*   ih_cols = (const int*)d_in[6];
  const float* ih_vals = (const float*)d_in[7];
  const int*   ho_rows = (const int*)d_in[8];
  const int*   ho_cols = (const int*)d_in[9];
  const float* ho_vals = (const float*)d_in[10];
  const float* ho_bias = (const float*)d_in[11];
  float* out = (float*)d_out;

  const int nnz_hh = in_sizes[1];
  const int nnz_ih = in_sizes[5];
  const int nnz_ho = in_sizes[8];

  // Workspace carve-up
  char* w = (char*)d_ws;
  size_t off = 0;
  auto alloc = [&](size_t bytes) -> void* {
    void* p = w + off;
    off += (bytes + 255) & ~(size_t)255;
    return p;
  };
  float* x2      = (float*)alloc(sizeof(float) * (size_t)Ii * Tt * Bb);        // 32 MB
  float* hAll    = (float*)alloc(sizeof(float) * (size_t)(Tt + 1) * Hh * Bb);  // 33 MB
  float* preAll  = (float*)alloc(sizeof(float) * (size_t)Tt * Hh * Bb);        // 32 MB
  int*  ih_rs  = (int*)alloc(4 * (size_t)(Hh + 1));
  int*  ih_cur = (int*)alloc(4 * (size_t)Hh);
  int2* ih_ent = (int2*)alloc(8 * (size_t)nnz_ih);
  int*  hh_rs  = (int*)alloc(4 * (size_t)(Hh + 1));
  int*  hh_cur = (int*)alloc(4 * (size_t)Hh);
  size_t hh_ent_bytes = 8 * ((size_t)nnz_hh + Hh + 8);   // padded (even row starts)
  int2* hh_ent = (int2*)alloc(hh_ent_bytes);
  int*  ho_rs  = (int*)alloc(4 * (size_t)(Oo + 1));
  int*  ho_cur = (int*)alloc(4 * (size_t)Oo);
  int2* ho_ent = (int2*)alloc(8 * (size_t)nnz_ho);
  float* out_tmp = x2;   // alias: x2 dead after preih_kernel

  // Init
  hipMemsetAsync(hAll, 0, sizeof(float) * (size_t)Hh * Bb, stream);   // h_{-1} = 0
  hipMemsetAsync(ih_cur, 0, 4 * (size_t)Hh, stream);
  hipMemsetAsync(hh_cur, 0, 4 * (size_t)Hh, stream);
  hipMemsetAsync(ho_cur, 0, 4 * (size_t)Oo, stream);
  hipMemsetAsync(hh_ent, 0, hh_ent_bytes, stream);       // zero pad slots -> val 0.0f

  // x -> (I,T,B)
  transpose_x_kernel<<<(Tt / 2) * (Ii / 64), 256, 0, stream>>>(x, x2);

  // CSR build (hh padded to even row starts for int4 pair loads)
  hist_kernel<<<1024, 256, 0, stream>>>(ih_rows, nnz_ih, ih_cur);
  hist_kernel<<<1024, 256, 0, stream>>>(hh_rows, nnz_hh, hh_cur);
  hist_kernel<<<1024, 256, 0, stream>>>(ho_rows, nnz_ho, ho_cur);
  scan_kernel<<<1, 1024, 0, stream>>>(ih_cur, Hh, ih_rs, 0);
  scan_kernel<<<1, 1024, 0, stream>>>(hh_cur, Hh, hh_rs, 1);
  scan_kernel<<<1, 1024, 0, stream>>>(ho_cur, Oo, ho_rs, 0);
  scatter_kernel<<<1024, 256, 0, stream>>>(ih_rows, ih_cols, ih_vals, nnz_ih, ih_cur, ih_ent);
  scatter_kernel<<<1024, 256, 0, stream>>>(hh_rows, hh_cols, hh_vals, nnz_hh, hh_cur, hh_ent);
  scatter_kernel<<<1024, 256, 0, stream>>>(ho_rows, ho_cols, ho_vals, nnz_ho, ho_cur, ho_ent);

  // pre[t][r][b] for all t (fully parallel)
  preih_kernel<<<2048, 256, 0, stream>>>(ih_rs, ih_ent, hh_bias, x2, preAll);

  // Recurrence: one dispatch per step (HW dispatch boundary = cross-XCD coherence,
  // ~50x cheaper than cooperative grid.sync)
  for (int t = 0; t < Tt; t++) {
    step_kernel<<<2048, 256, 0, stream>>>(
        hh_rs, hh_cur, (const int4*)hh_ent,
        preAll + (size_t)t * Hh * Bb,
        hAll + (size_t)t * Hh * Bb,
        hAll + (size_t)(t + 1) * Hh * Bb);
  }

  // Output spmm + final transpose
  out_kernel<<<2048, 256, 0, stream>>>(ho_rs, ho_ent, ho_bias, hAll, out_tmp);
  transpose_out_kernel<<<Tt * (Oo / 64), 256, 0, stream>>>(out_tmp, out);

  (void)n_in; (void)out_size; (void)ws_size;
}

// Round 4
// 1113.525 us; speedup vs baseline: 5.7925x; 1.2190x over previous
//
#include <hip/hip_runtime.h>

// Problem constants (fixed by the reference)
constexpr int Bb = 32;     // batch
constexpr int Tt = 32;     // time steps
constexpr int Ii = 8192;   // input dim
constexpr int Hh = 8192;   // hidden dim
constexpr int Oo = 2048;   // output dim
constexpr int TB = Tt * Bb;  // 1024
constexpr int TCH = 4;       // timesteps per preih chunk (4 MB x2 slice = 1 XCD L2)
constexpr int NCH = Tt / TCH;  // 8 chunks

// ---------------- x transpose: (B,T,I) -> (I,T,B) ----------------
__global__ void transpose_x_kernel(const float* __restrict__ x, float* __restrict__ x2) {
  // grid = (Tt/2) * (Ii/64) = 2048 blocks, 256 threads
  int blk = blockIdx.x;
  int tp = blk >> 7;             // Ii/64 = 128
  int ib = blk & 127;
  int t0 = tp * 2;
  int i0 = ib * 64;
  __shared__ float lds[64][65];
  int tid = threadIdx.x;
  for (int idx = tid; idx < 64 * 64; idx += 256) {
    int row = idx >> 6;          // tt*32 + b
    int il  = idx & 63;          // coalesced reads along i
    int tt = row >> 5, bb = row & 31;
    lds[il][row] = x[(size_t)bb * Tt * Ii + (size_t)(t0 + tt) * Ii + i0 + il];
  }
  __syncthreads();
  for (int idx = tid; idx < 64 * 64; idx += 256) {
    int il = idx >> 6;
    int row = idx & 63;          // contiguous writes
    x2[(size_t)(i0 + il) * TB + t0 * Bb + row] = lds[il][row];
  }
}

// ---------------- CSR build (merged kernels) ----------------
__global__ void hist3_kernel(const int* __restrict__ r1, int n1, int* __restrict__ c1,
                             const int* __restrict__ r2, int n2, int* __restrict__ c2,
                             const int* __restrict__ r3, int n3, int* __restrict__ c3) {
  int i = blockIdx.x * blockDim.x + threadIdx.x;
  int stride = gridDim.x * blockDim.x;
  for (int j = i; j < n1; j += stride) atomicAdd(&c1[r1[j]], 1);
  for (int j = i; j < n2; j += stride) atomicAdd(&c2[r2[j]], 1);
  for (int j = i; j < n3; j += stride) atomicAdd(&c3[r3[j]], 1);
}

// Exclusive scan; pad!=0 rounds each row count up to even (16B-aligned row starts
// in the int2 entry array -> int4 pair loads). One block per array.
__global__ void scan3_kernel(int* __restrict__ c1, int n1, int* __restrict__ r1, int p1,
                             int* __restrict__ c2, int n2, int* __restrict__ r2, int p2,
                             int* __restrict__ c3, int n3, int* __restrict__ r3, int p3) {
  int* cnt_cursor; int n; int* row_start; int pad;
  if (blockIdx.x == 0)      { cnt_cursor = c1; n = n1; row_start = r1; pad = p1; }
  else if (blockIdx.x == 1) { cnt_cursor = c2; n = n2; row_start = r2; pad = p2; }
  else                      { cnt_cursor = c3; n = n3; row_start = r3; pad = p3; }
  __shared__ int sums[1024];
  int tid = threadIdx.x;
  int chunk = (n + 1023) >> 10;
  int base = tid * chunk;
  int s = 0;
  for (int i = 0; i < chunk; i++) {
    int idx = base + i;
    if (idx < n) {
      int v = cnt_cursor[idx];
      s += pad ? ((v + 1) & ~1) : v;
    }
  }
  sums[tid] = s;
  __syncthreads();
  for (int off = 1; off < 1024; off <<= 1) {
    int other = (tid >= off) ? sums[tid - off] : 0;
    __syncthreads();
    sums[tid] += other;
    __syncthreads();
  }
  int run = sums[tid] - s;
  for (int i = 0; i < chunk; i++) {
    int idx = base + i;
    if (idx < n) {
      int v = cnt_cursor[idx];
      row_start[idx] = run;
      cnt_cursor[idx] = run;
      run += pad ? ((v + 1) & ~1) : v;
    }
  }
  if (tid == 1023) row_start[n] = sums[1023];
}

__global__ void scatter3_kernel(
    const int* __restrict__ r1, const int* __restrict__ co1, const float* __restrict__ v1,
    int n1, int* __restrict__ cu1, int2* __restrict__ e1,
    const int* __restrict__ r2, const int* __restrict__ co2, const float* __restrict__ v2,
    int n2, int* __restrict__ cu2, int2* __restrict__ e2,
    const int* __restrict__ r3, const int* __restrict__ co3, const float* __restrict__ v3,
    int n3, int* __restrict__ cu3, int2* __restrict__ e3) {
  int i = blockIdx.x * blockDim.x + threadIdx.x;
  int stride = gridDim.x * blockDim.x;
  for (int j = i; j < n1; j += stride) {
    int pos = atomicAdd(&cu1[r1[j]], 1);
    e1[pos] = make_int2(co1[j], __float_as_int(v1[j]));
  }
  for (int j = i; j < n2; j += stride) {
    int pos = atomicAdd(&cu2[r2[j]], 1);
    e2[pos] = make_int2(co2[j], __float_as_int(v2[j]));
  }
  for (int j = i; j < n3; j += stride) {
    int pos = atomicAdd(&cu3[r3[j]], 1);
    e3[pos] = make_int2(co3[j], __float_as_int(v3[j]));
  }
}

// ---------------- preIH, time-chunked for L2 residency ----------------
// pre[t][r][b] = bias[r] + sum_j ih_val[j] * x2[col_j][t][b], chunk = TCH timesteps.
// Wave = (chunk c, row r); lane covers (tt = lane>>4, b-pair = 2*(lane&15)) via
// float2 gathers (512 B per entry). Consecutive blocks share a chunk so each
// XCD's L2 holds the 4 MB x2 slice for the chunk it's sweeping.
__global__ void __launch_bounds__(256, 8) preih_kernel(
    const int* __restrict__ ih_rs, const int* __restrict__ ih_cur,
    const int4* __restrict__ ih_entp,
    const float* __restrict__ hh_bias, const float* __restrict__ x2,
    float* __restrict__ preAll) {
  int wave = (blockIdx.x * 256 + threadIdx.x) >> 6;  // 0 .. NCH*Hh-1
  int c = wave >> 13;            // 8192 waves per chunk
  int r = wave & (Hh - 1);
  int lane = threadIdx.x & 63;
  int t0 = c * TCH;
  int s0  = __builtin_amdgcn_readfirstlane(ih_rs[r]);       // even (padded)
  int cnt = __builtin_amdgcn_readfirstlane(ih_cur[r]) - s0; // actual entries
  int np = (cnt + 1) >> 1;                                  // pairs; pad slot zeroed
  const int4* ep = ih_entp + (s0 >> 1);
  const float* xch = x2 + t0 * Bb;   // chunk base; column i at + i*TB

  float2 a0 = {0.f, 0.f}, a1 = {0.f, 0.f}, a2 = {0.f, 0.f}, a3 = {0.f, 0.f};
  int m = 0;
  for (; m + 2 <= np; m += 2) {
    int4 e01 = ep[m];
    int4 e23 = ep[m + 1];
    const float2* p0 = (const float2*)(xch + (size_t)e01.x * TB);
    const float2* p1 = (const float2*)(xch + (size_t)e01.z * TB);
    const float2* p2 = (const float2*)(xch + (size_t)e23.x * TB);
    const float2* p3 = (const float2*)(xch + (size_t)e23.z * TB);
    float2 x0 = p0[lane], x1 = p1[lane], x2v = p2[lane], x3 = p3[lane];
    float v0 = __int_as_float(e01.y), v1 = __int_as_float(e01.w);
    float v2 = __int_as_float(e23.y), v3 = __int_as_float(e23.w);
    a0.x += v0 * x0.x;  a0.y += v0 * x0.y;
    a1.x += v1 * x1.x;  a1.y += v1 * x1.y;
    a2.x += v2 * x2v.x; a2.y += v2 * x2v.y;
    a3.x += v3 * x3.x;  a3.y += v3 * x3.y;
  }
  if (m < np) {
    int4 e01 = ep[m];
    const float2* p0 = (const float2*)(xch + (size_t)e01.x * TB);
    const float2* p1 = (const float2*)(xch + (size_t)e01.z * TB);
    float2 x0 = p0[lane], x1 = p1[lane];
    float v0 = __int_as_float(e01.y), v1 = __int_as_float(e01.w);
    a0.x += v0 * x0.x; a0.y += v0 * x0.y;
    a1.x += v1 * x1.x; a1.y += v1 * x1.y;
  }
  float bias = hh_bias[r];
  float2 acc;
  acc.x = ((a0.x + a1.x) + (a2.x + a3.x)) + bias;
  acc.y = ((a0.y + a1.y) + (a2.y + a3.y)) + bias;
  int t = t0 + (lane >> 4);
  int b0 = (lane & 15) * 2;
  *(float2*)(preAll + ((size_t)t * Hh + r) * Bb + b0) = acc;
}

// ---------------- One recurrence step: h_{t+1} = sigmoid(pre_t + HH @ h_t) ----------------
__global__ void __launch_bounds__(256, 8) step_kernel(
    const int* __restrict__ hh_rs, const int* __restrict__ hh_cur,
    const int4* __restrict__ hh_entp,
    const float* __restrict__ pre_t,
    const float* __restrict__ hprev,
    float* __restrict__ hnext) {
  int r = (blockIdx.x * 256 + threadIdx.x) >> 6;   // one wave per row
  int lane = threadIdx.x & 63;
  int h = lane >> 5, b = lane & 31;
  int s0  = __builtin_amdgcn_readfirstlane(hh_rs[r]);       // even
  int cnt = __builtin_amdgcn_readfirstlane(hh_cur[r]) - s0;
  int np = (cnt + 1) >> 1;                                  // pad pair-half zeroed
  const int4* ep = hh_entp + (s0 >> 1);
  float pre = pre_t[r * Bb + b];

  float a0 = 0.f, a1 = 0.f, a2 = 0.f, a3 = 0.f;
  int m = 0;
  for (; m + 4 <= np; m += 4) {
    int4 e0 = ep[m];
    int4 e1 = ep[m + 1];
    int4 e2 = ep[m + 2];
    int4 e3 = ep[m + 3];
    int   c0 = h ? e0.z : e0.x;  float v0 = __int_as_float(h ? e0.w : e0.y);
    int   c1 = h ? e1.z : e1.x;  float v1 = __int_as_float(h ? e1.w : e1.y);
    int   c2 = h ? e2.z : e2.x;  float v2 = __int_as_float(h ? e2.w : e2.y);
    int   c3 = h ? e3.z : e3.x;  float v3 = __int_as_float(h ? e3.w : e3.y);
    a0 += v0 * hprev[(c0 << 5) + b];
    a1 += v1 * hprev[(c1 << 5) + b];
    a2 += v2 * hprev[(c2 << 5) + b];
    a3 += v3 * hprev[(c3 << 5) + b];
  }
  for (; m < np; m++) {
    int4 e = ep[m];
    int   c = h ? e.z : e.x;  float v = __int_as_float(h ? e.w : e.y);
    a0 += v * hprev[(c << 5) + b];
  }
  float acc = (a0 + a1) + (a2 + a3);
  acc += __shfl_xor(acc, 32, 64);
  float hv = 1.0f / (1.0f + __expf(-(pre + acc)));
  if (h == 0) hnext[(r << 5) + b] = hv;
}

// ---------------- Output spmm over all (t, o) rows ----------------
__global__ void out_kernel(const int* __restrict__ ho_rs, const int2* __restrict__ ho_ent,
                           const float* __restrict__ ho_bias, const float* __restrict__ hAll,
                           float* __restrict__ out_tmp) {
  int gtid = blockIdx.x * blockDim.x + threadIdx.x;
  int wave = gtid >> 6;
  int nwaves = (gridDim.x * blockDim.x) >> 6;
  int lane = threadIdx.x & 63;
  int half = lane >> 5, b = lane & 31;
  for (int p = wave; p < Tt * Oo; p += nwaves) {
    int t = p >> 11;          // Oo = 2048
    int r = p & (Oo - 1);
    const float* hcur = hAll + (size_t)(t + 1) * (Hh * Bb);
    float a0 = (half == 0) ? ho_bias[r] : 0.0f;
    float a1 = 0.f, a2 = 0.f, a3 = 0.f;
    int s0 = ho_rs[r], s1 = ho_rs[r + 1];
    int nh = (s1 - s0 - half + 1) >> 1;
    int m = 0;
    for (; m + 4 <= nh; m += 4) {
      int p0 = s0 + half + 2 * m;
      int2 e0 = ho_ent[p0];
      int2 e1 = ho_ent[p0 + 2];
      int2 e2 = ho_ent[p0 + 4];
      int2 e3 = ho_ent[p0 + 6];
      a0 += __int_as_float(e0.y) * hcur[e0.x * Bb + b];
      a1 += __int_as_float(e1.y) * hcur[e1.x * Bb + b];
      a2 += __int_as_float(e2.y) * hcur[e2.x * Bb + b];
      a3 += __int_as_float(e3.y) * hcur[e3.x * Bb + b];
    }
    for (; m < nh; m++) {
      int2 e = ho_ent[s0 + half + 2 * m];
      a0 += __int_as_float(e.y) * hcur[e.x * Bb + b];
    }
    float acc = (a0 + a1) + (a2 + a3);
    acc += __shfl_xor(acc, 32, 64);
    if (half == 0) out_tmp[(size_t)p * Bb + b] = acc;
  }
}

// ---------------- out transpose: (T,O,B) -> (B,T,O) ----------------
__global__ void transpose_out_kernel(const float* __restrict__ out_tmp, float* __restrict__ dout) {
  int blk = blockIdx.x;              // grid = Tt * (Oo/64) = 1024
  int t  = blk >> 5;
  int o0 = (blk & 31) << 6;
  __shared__ float lds[64][33];
  int tid = threadIdx.x;
  for (int idx = tid; idx < 64 * 32; idx += 256) {
    int ol = idx >> 5, bb = idx & 31;
    lds[ol][bb] = out_tmp[(size_t)t * Oo * Bb + (size_t)(o0 + ol) * Bb + bb];
  }
  __syncthreads();
  for (int idx = tid; idx < 32 * 64; idx += 256) {
    int bb = idx >> 6, ol = idx & 63;
    dout[(size_t)bb * Tt * Oo + (size_t)t * Oo + o0 + ol] = lds[ol][bb];
  }
}

extern "C" void kernel_launch(void* const* d_in, const int* in_sizes, int n_in,
                              void* d_out, int out_size, void* d_ws, size_t ws_size,
                              hipStream_t stream) {
  const float* x       = (const float*)d_in[0];
  const int*   hh_rows = (const int*)d_in[1];
  const int*   hh_cols = (const int*)d_in[2];
  const float* hh_vals = (const float*)d_in[3];
  const float* hh_bias = (const float*)d_in[4];
  const int*   ih_rows = (const int*)d_in[5];
  const int*   ih_cols = (const int*)d_in[6];
  const float* ih_vals = (const float*)d_in[7];
  const int*   ho_rows = (const int*)d_in[8];
  const int*   ho_cols = (const int*)d_in[9];
  const float* ho_vals = (const float*)d_in[10];
  const float* ho_bias = (const float*)d_in[11];
  float* out = (float*)d_out;

  const int nnz_hh = in_sizes[1];
  const int nnz_ih = in_sizes[5];
  const int nnz_ho = in_sizes[8];

  // Workspace carve-up
  char* w = (char*)d_ws;
  size_t off = 0;
  auto alloc = [&](size_t bytes) -> void* {
    void* p = w + off;
    off += (bytes + 255) & ~(size_t)255;
    return p;
  };
  float* x2      = (float*)alloc(sizeof(float) * (size_t)Ii * TB);              // 32 MB
  float* hAll    = (float*)alloc(sizeof(float) * (size_t)(Tt + 1) * Hh * Bb);   // 33 MB
  float* preAll  = (float*)alloc(sizeof(float) * (size_t)Tt * Hh * Bb);         // 32 MB
  int*  ih_rs  = (int*)alloc(4 * (size_t)(Hh + 1));
  int*  hh_rs  = (int*)alloc(4 * (size_t)(Hh + 1));
  int*  ho_rs  = (int*)alloc(4 * (size_t)(Oo + 1));
  int*  cur_all = (int*)alloc(4 * (size_t)(Hh + Hh + Oo));  // contiguous: 1 memset
  int*  ih_cur = cur_all;
  int*  hh_cur = cur_all + Hh;
  int*  ho_cur = cur_all + 2 * Hh;
  size_t ent_off0 = off;
  int2* ih_ent = (int2*)alloc(8 * ((size_t)nnz_ih + Hh + 8));   // pair-padded
  int2* hh_ent = (int2*)alloc(8 * ((size_t)nnz_hh + Hh + 8));   // pair-padded
  size_t ent_bytes = off - ent_off0;                            // zero both in 1 memset
  int2* ho_ent = (int2*)alloc(8 * (size_t)nnz_ho);
  float* out_tmp = x2;   // alias: x2 dead after preih_kernel

  // Init (3 memsets)
  hipMemsetAsync(hAll, 0, sizeof(float) * (size_t)Hh * Bb, stream);   // h_{-1} = 0
  hipMemsetAsync(cur_all, 0, 4 * (size_t)(Hh + Hh + Oo), stream);
  hipMemsetAsync(w + ent_off0, 0, ent_bytes, stream);                 // zero pad slots

  // x -> (I,T,B)
  transpose_x_kernel<<<(Tt / 2) * (Ii / 64), 256, 0, stream>>>(x, x2);

  // CSR build (ih & hh pair-padded for int4 loads)
  hist3_kernel<<<1024, 256, 0, stream>>>(ih_rows, nnz_ih, ih_cur,
                                         hh_rows, nnz_hh, hh_cur,
                                         ho_rows, nnz_ho, ho_cur);
  scan3_kernel<<<3, 1024, 0, stream>>>(ih_cur, Hh, ih_rs, 1,
                                       hh_cur, Hh, hh_rs, 1,
                                       ho_cur, Oo, ho_rs, 0);
  scatter3_kernel<<<1024, 256, 0, stream>>>(
      ih_rows, ih_cols, ih_vals, nnz_ih, ih_cur, ih_ent,
      hh_rows, hh_cols, hh_vals, nnz_hh, hh_cur, hh_ent,
      ho_rows, ho_cols, ho_vals, nnz_ho, ho_cur, ho_ent);

  // pre[t][r][b] for all t, time-chunked (NCH chunks x Hh rows, wave each)
  preih_kernel<<<NCH * Hh / 4, 256, 0, stream>>>(
      ih_rs, ih_cur, (const int4*)ih_ent, hh_bias, x2, preAll);

  // Recurrence: one dispatch per step
  for (int t = 0; t < Tt; t++) {
    step_kernel<<<Hh / 4, 256, 0, stream>>>(
        hh_rs, hh_cur, (const int4*)hh_ent,
        preAll + (size_t)t * Hh * Bb,
        hAll + (size_t)t * Hh * Bb,
        hAll + (size_t)(t + 1) * Hh * Bb);
  }

  // Output spmm + final transpose
  out_kernel<<<2048, 256, 0, stream>>>(ho_rs, ho_ent, ho_bias, hAll, out_tmp);
  transpose_out_kernel<<<Tt * (Oo / 64), 256, 0, stream>>>(out_tmp, out);

  (void)n_in; (void)out_size; (void)ws_size;
}

// Round 5
// 988.103 us; speedup vs baseline: 6.5277x; 1.1269x over previous
//
#include <hip/hip_runtime.h>

// Problem constants (fixed by the reference)
constexpr int Bb = 32;     // batch
constexpr int Tt = 32;     // time steps
constexpr int Ii = 8192;   // input dim
constexpr int Hh = 8192;   // hidden dim
constexpr int Oo = 2048;   // output dim
constexpr int TB = Tt * Bb;  // 1024
constexpr int TCH = 4;       // timesteps per preih chunk (4 MB x2 slice = 1 XCD L2)
constexpr int NCH = Tt / TCH;  // 8 chunks

// ---------------- x transpose: (B,T,I) -> (I,T,B) ----------------
__global__ void transpose_x_kernel(const float* __restrict__ x, float* __restrict__ x2) {
  // grid = (Tt/2) * (Ii/64) = 2048 blocks, 256 threads
  int blk = blockIdx.x;
  int tp = blk >> 7;             // Ii/64 = 128
  int ib = blk & 127;
  int t0 = tp * 2;
  int i0 = ib * 64;
  __shared__ float lds[64][65];
  int tid = threadIdx.x;
  for (int idx = tid; idx < 64 * 64; idx += 256) {
    int row = idx >> 6;          // tt*32 + b
    int il  = idx & 63;          // coalesced reads along i
    int tt = row >> 5, bb = row & 31;
    lds[il][row] = x[(size_t)bb * Tt * Ii + (size_t)(t0 + tt) * Ii + i0 + il];
  }
  __syncthreads();
  for (int idx = tid; idx < 64 * 64; idx += 256) {
    int il = idx >> 6;
    int row = idx & 63;          // contiguous writes
    x2[(size_t)(i0 + il) * TB + t0 * Bb + row] = lds[il][row];
  }
}

// ---------------- CSR build (merged kernels) ----------------
__global__ void hist3_kernel(const int* __restrict__ r1, int n1, int* __restrict__ c1,
                             const int* __restrict__ r2, int n2, int* __restrict__ c2,
                             const int* __restrict__ r3, int n3, int* __restrict__ c3) {
  int i = blockIdx.x * blockDim.x + threadIdx.x;
  int stride = gridDim.x * blockDim.x;
  for (int j = i; j < n1; j += stride) atomicAdd(&c1[r1[j]], 1);
  for (int j = i; j < n2; j += stride) atomicAdd(&c2[r2[j]], 1);
  for (int j = i; j < n3; j += stride) atomicAdd(&c3[r3[j]], 1);
}

// Exclusive scan; pad!=0 rounds each row count up to even (16B-aligned row starts
// in the int2 entry array -> int4 pair loads). One block per array.
__global__ void scan3_kernel(int* __restrict__ c1, int n1, int* __restrict__ r1, int p1,
                             int* __restrict__ c2, int n2, int* __restrict__ r2, int p2,
                             int* __restrict__ c3, int n3, int* __restrict__ r3, int p3) {
  int* cnt_cursor; int n; int* row_start; int pad;
  if (blockIdx.x == 0)      { cnt_cursor = c1; n = n1; row_start = r1; pad = p1; }
  else if (blockIdx.x == 1) { cnt_cursor = c2; n = n2; row_start = r2; pad = p2; }
  else                      { cnt_cursor = c3; n = n3; row_start = r3; pad = p3; }
  __shared__ int sums[1024];
  int tid = threadIdx.x;
  int chunk = (n + 1023) >> 10;
  int base = tid * chunk;
  int s = 0;
  for (int i = 0; i < chunk; i++) {
    int idx = base + i;
    if (idx < n) {
      int v = cnt_cursor[idx];
      s += pad ? ((v + 1) & ~1) : v;
    }
  }
  sums[tid] = s;
  __syncthreads();
  for (int off = 1; off < 1024; off <<= 1) {
    int other = (tid >= off) ? sums[tid - off] : 0;
    __syncthreads();
    sums[tid] += other;
    __syncthreads();
  }
  int run = sums[tid] - s;
  for (int i = 0; i < chunk; i++) {
    int idx = base + i;
    if (idx < n) {
      int v = cnt_cursor[idx];
      row_start[idx] = run;
      cnt_cursor[idx] = run;
      run += pad ? ((v + 1) & ~1) : v;
    }
  }
  if (tid == 1023) row_start[n] = sums[1023];
}

__global__ void scatter3_kernel(
    const int* __restrict__ r1, const int* __restrict__ co1, const float* __restrict__ v1,
    int n1, int* __restrict__ cu1, int2* __restrict__ e1,
    const int* __restrict__ r2, const int* __restrict__ co2, const float* __restrict__ v2,
    int n2, int* __restrict__ cu2, int2* __restrict__ e2,
    const int* __restrict__ r3, const int* __restrict__ co3, const float* __restrict__ v3,
    int n3, int* __restrict__ cu3, int2* __restrict__ e3) {
  int i = blockIdx.x * blockDim.x + threadIdx.x;
  int stride = gridDim.x * blockDim.x;
  for (int j = i; j < n1; j += stride) {
    int pos = atomicAdd(&cu1[r1[j]], 1);
    e1[pos] = make_int2(co1[j], __float_as_int(v1[j]));
  }
  for (int j = i; j < n2; j += stride) {
    int pos = atomicAdd(&cu2[r2[j]], 1);
    e2[pos] = make_int2(co2[j], __float_as_int(v2[j]));
  }
  for (int j = i; j < n3; j += stride) {
    int pos = atomicAdd(&cu3[r3[j]], 1);
    e3[pos] = make_int2(co3[j], __float_as_int(v3[j]));
  }
}

// ---------------- preIH, time-chunked for L2 residency ----------------
__global__ void __launch_bounds__(256, 8) preih_kernel(
    const int* __restrict__ ih_rs, const int* __restrict__ ih_cur,
    const int4* __restrict__ ih_entp,
    const float* __restrict__ hh_bias, const float* __restrict__ x2,
    float* __restrict__ preAll) {
  int wave = (blockIdx.x * 256 + threadIdx.x) >> 6;  // 0 .. NCH*Hh-1
  int c = wave >> 13;            // 8192 waves per chunk
  int r = wave & (Hh - 1);
  int lane = threadIdx.x & 63;
  int t0 = c * TCH;
  int s0  = __builtin_amdgcn_readfirstlane(ih_rs[r]);       // even (padded)
  int cnt = __builtin_amdgcn_readfirstlane(ih_cur[r]) - s0; // actual entries
  int np = (cnt + 1) >> 1;                                  // pairs; pad slot zeroed
  const int4* ep = ih_entp + (s0 >> 1);
  const float* xch = x2 + t0 * Bb;   // chunk base; column i at + i*TB

  float2 a0 = {0.f, 0.f}, a1 = {0.f, 0.f}, a2 = {0.f, 0.f}, a3 = {0.f, 0.f};
  int m = 0;
  for (; m + 2 <= np; m += 2) {
    int4 e01 = ep[m];
    int4 e23 = ep[m + 1];
    const float2* p0 = (const float2*)(xch + (size_t)e01.x * TB);
    const float2* p1 = (const float2*)(xch + (size_t)e01.z * TB);
    const float2* p2 = (const float2*)(xch + (size_t)e23.x * TB);
    const float2* p3 = (const float2*)(xch + (size_t)e23.z * TB);
    float2 x0 = p0[lane], x1 = p1[lane], x2v = p2[lane], x3 = p3[lane];
    float v0 = __int_as_float(e01.y), v1 = __int_as_float(e01.w);
    float v2 = __int_as_float(e23.y), v3 = __int_as_float(e23.w);
    a0.x += v0 * x0.x;  a0.y += v0 * x0.y;
    a1.x += v1 * x1.x;  a1.y += v1 * x1.y;
    a2.x += v2 * x2v.x; a2.y += v2 * x2v.y;
    a3.x += v3 * x3.x;  a3.y += v3 * x3.y;
  }
  if (m < np) {
    int4 e01 = ep[m];
    const float2* p0 = (const float2*)(xch + (size_t)e01.x * TB);
    const float2* p1 = (const float2*)(xch + (size_t)e01.z * TB);
    float2 x0 = p0[lane], x1 = p1[lane];
    float v0 = __int_as_float(e01.y), v1 = __int_as_float(e01.w);
    a0.x += v0 * x0.x; a0.y += v0 * x0.y;
    a1.x += v1 * x1.x; a1.y += v1 * x1.y;
  }
  float bias = hh_bias[r];
  float2 acc;
  acc.x = ((a0.x + a1.x) + (a2.x + a3.x)) + bias;
  acc.y = ((a0.y + a1.y) + (a2.y + a3.y)) + bias;
  int t = t0 + (lane >> 4);
  int b0 = (lane & 15) * 2;
  *(float2*)(preAll + ((size_t)t * Hh + r) * Bb + b0) = acc;
}

// ---------------- One recurrence step: h_{t+1} = sigmoid(pre_t + HH @ h_t) ----------------
__global__ void __launch_bounds__(256, 8) step_kernel(
    const int* __restrict__ hh_rs, const int* __restrict__ hh_cur,
    const int4* __restrict__ hh_entp,
    const float* __restrict__ pre_t,
    const float* __restrict__ hprev,
    float* __restrict__ hnext) {
  int r = (blockIdx.x * 256 + threadIdx.x) >> 6;   // one wave per row
  int lane = threadIdx.x & 63;
  int h = lane >> 5, b = lane & 31;
  int s0  = __builtin_amdgcn_readfirstlane(hh_rs[r]);       // even
  int cnt = __builtin_amdgcn_readfirstlane(hh_cur[r]) - s0;
  int np = (cnt + 1) >> 1;                                  // pad pair-half zeroed
  const int4* ep = hh_entp + (s0 >> 1);
  float pre = pre_t[r * Bb + b];

  float a0 = 0.f, a1 = 0.f, a2 = 0.f, a3 = 0.f;
  int m = 0;
  for (; m + 4 <= np; m += 4) {
    int4 e0 = ep[m];
    int4 e1 = ep[m + 1];
    int4 e2 = ep[m + 2];
    int4 e3 = ep[m + 3];
    int   c0 = h ? e0.z : e0.x;  float v0 = __int_as_float(h ? e0.w : e0.y);
    int   c1 = h ? e1.z : e1.x;  float v1 = __int_as_float(h ? e1.w : e1.y);
    int   c2 = h ? e2.z : e2.x;  float v2 = __int_as_float(h ? e2.w : e2.y);
    int   c3 = h ? e3.z : e3.x;  float v3 = __int_as_float(h ? e3.w : e3.y);
    a0 += v0 * hprev[(c0 << 5) + b];
    a1 += v1 * hprev[(c1 << 5) + b];
    a2 += v2 * hprev[(c2 << 5) + b];
    a3 += v3 * hprev[(c3 << 5) + b];
  }
  for (; m < np; m++) {
    int4 e = ep[m];
    int   c = h ? e.z : e.x;  float v = __int_as_float(h ? e.w : e.y);
    a0 += v * hprev[(c << 5) + b];
  }
  float acc = (a0 + a1) + (a2 + a3);
  acc += __shfl_xor(acc, 32, 64);
  float hv = 1.0f / (1.0f + __expf(-(pre + acc)));
  if (h == 0) hnext[(r << 5) + b] = hv;
}

// ---------------- Output spmm, XCD-partitioned by time ----------------
// xcd = blockIdx&7 owns t-group [4*xcd, 4*xcd+4). Each wave handles an o-row
// for all 4 group timesteps: entry pair loaded once (registers), 4 gathers ->
// per-XCD hot set = 4 h-slices (4 MB, L2-resident) + streamed entries.
__global__ void __launch_bounds__(256, 8) out_kernel(
    const int* __restrict__ ho_rs, const int* __restrict__ ho_cur,
    const int4* __restrict__ ho_entp,
    const float* __restrict__ ho_bias, const float* __restrict__ hAll,
    float* __restrict__ out_tmp) {
  int xcd = blockIdx.x & 7;
  int w   = (blockIdx.x >> 3) * 4 + (threadIdx.x >> 6);  // 0..1023 within XCD
  int lane = threadIdx.x & 63;
  int h = lane >> 5, b = lane & 31;
  int t0 = xcd * 4;
  const float* hbase = hAll + (size_t)(t0 + 1) * (Hh * Bb);  // h for step t0
  constexpr size_t HS = (size_t)Hh * Bb;

  for (int o = w; o < Oo; o += 1024) {   // 2 o-rows per wave
    int s0  = __builtin_amdgcn_readfirstlane(ho_rs[o]);       // even (padded)
    int cnt = __builtin_amdgcn_readfirstlane(ho_cur[o]) - s0;
    int np = (cnt + 1) >> 1;                                  // pad slot zeroed
    const int4* ep = ho_entp + (s0 >> 1);
    float bias = (h == 0) ? ho_bias[o] : 0.f;
    float A0 = bias, A1 = bias, A2 = bias, A3 = bias;
    float B0 = 0.f, B1 = 0.f, B2 = 0.f, B3 = 0.f;
    int m = 0;
    for (; m + 2 <= np; m += 2) {        // 2 pairs -> 8 gathers in flight
      int4 ea = ep[m];
      int4 eb = ep[m + 1];
      int ca = (h ? ea.z : ea.x);  float va = __int_as_float(h ? ea.w : ea.y);
      int cb = (h ? eb.z : eb.x);  float vb = __int_as_float(h ? eb.w : eb.y);
      const float* pa = hbase + ((size_t)ca << 5) + b;
      const float* pb = hbase + ((size_t)cb << 5) + b;
      A0 += va * pa[0];
      A1 += va * pa[HS];
      A2 += va * pa[2 * HS];
      A3 += va * pa[3 * HS];
      B0 += vb * pb[0];
      B1 += vb * pb[HS];
      B2 += vb * pb[2 * HS];
      B3 += vb * pb[3 * HS];
    }
    if (m < np) {
      int4 ea = ep[m];
      int ca = (h ? ea.z : ea.x);  float va = __int_as_float(h ? ea.w : ea.y);
      const float* pa = hbase + ((size_t)ca << 5) + b;
      A0 += va * pa[0];
      A1 += va * pa[HS];
      A2 += va * pa[2 * HS];
      A3 += va * pa[3 * HS];
    }
    A0 += B0; A1 += B1; A2 += B2; A3 += B3;
    A0 += __shfl_xor(A0, 32, 64);
    A1 += __shfl_xor(A1, 32, 64);
    A2 += __shfl_xor(A2, 32, 64);
    A3 += __shfl_xor(A3, 32, 64);
    if (h == 0) {
      out_tmp[((size_t)(t0 + 0) * Oo + o) * Bb + b] = A0;
      out_tmp[((size_t)(t0 + 1) * Oo + o) * Bb + b] = A1;
      out_tmp[((size_t)(t0 + 2) * Oo + o) * Bb + b] = A2;
      out_tmp[((size_t)(t0 + 3) * Oo + o) * Bb + b] = A3;
    }
  }
}

// ---------------- out transpose: (T,O,B) -> (B,T,O) ----------------
__global__ void transpose_out_kernel(const float* __restrict__ out_tmp, float* __restrict__ dout) {
  int blk = blockIdx.x;              // grid = Tt * (Oo/64) = 1024
  int t  = blk >> 5;
  int o0 = (blk & 31) << 6;
  __shared__ float lds[64][33];
  int tid = threadIdx.x;
  for (int idx = tid; idx < 64 * 32; idx += 256) {
    int ol = idx >> 5, bb = idx & 31;
    lds[ol][bb] = out_tmp[(size_t)t * Oo * Bb + (size_t)(o0 + ol) * Bb + bb];
  }
  __syncthreads();
  for (int idx = tid; idx < 32 * 64; idx += 256) {
    int bb = idx >> 6, ol = idx & 63;
    dout[(size_t)bb * Tt * Oo + (size_t)t * Oo + o0 + ol] = lds[ol][bb];
  }
}

extern "C" void kernel_launch(void* const* d_in, const int* in_sizes, int n_in,
                              void* d_out, int out_size, void* d_ws, size_t ws_size,
                              hipStream_t stream) {
  const float* x       = (const float*)d_in[0];
  const int*   hh_rows = (const int*)d_in[1];
  const int*   hh_cols = (const int*)d_in[2];
  const float* hh_vals = (const float*)d_in[3];
  const float* hh_bias = (const float*)d_in[4];
  const int*   ih_rows = (const int*)d_in[5];
  const int*   ih_cols = (const int*)d_in[6];
  const float* ih_vals = (const float*)d_in[7];
  const int*   ho_rows = (const int*)d_in[8];
  const int*   ho_cols = (const int*)d_in[9];
  const float* ho_vals = (const float*)d_in[10];
  const float* ho_bias = (const float*)d_in[11];
  float* out = (float*)d_out;

  const int nnz_hh = in_sizes[1];
  const int nnz_ih = in_sizes[5];
  const int nnz_ho = in_sizes[8];

  // Workspace carve-up
  char* w = (char*)d_ws;
  size_t off = 0;
  auto alloc = [&](size_t bytes) -> void* {
    void* p = w + off;
    off += (bytes + 255) & ~(size_t)255;
    return p;
  };
  float* x2      = (float*)alloc(sizeof(float) * (size_t)Ii * TB);              // 32 MB
  float* hAll    = (float*)alloc(sizeof(float) * (size_t)(Tt + 1) * Hh * Bb);   // 33 MB
  float* preAll  = (float*)alloc(sizeof(float) * (size_t)Tt * Hh * Bb);         // 32 MB
  int*  ih_rs  = (int*)alloc(4 * (size_t)(Hh + 1));
  int*  hh_rs  = (int*)alloc(4 * (size_t)(Hh + 1));
  int*  ho_rs  = (int*)alloc(4 * (size_t)(Oo + 1));
  int*  cur_all = (int*)alloc(4 * (size_t)(Hh + Hh + Oo));  // contiguous: 1 memset
  int*  ih_cur = cur_all;
  int*  hh_cur = cur_all + Hh;
  int*  ho_cur = cur_all + 2 * Hh;
  size_t ent_off0 = off;
  int2* ih_ent = (int2*)alloc(8 * ((size_t)nnz_ih + Hh + 8));   // pair-padded
  int2* hh_ent = (int2*)alloc(8 * ((size_t)nnz_hh + Hh + 8));   // pair-padded
  int2* ho_ent = (int2*)alloc(8 * ((size_t)nnz_ho + Oo + 8));   // pair-padded
  size_t ent_bytes = off - ent_off0;                            // zero all pads: 1 memset
  float* out_tmp = x2;   // alias: x2 dead after preih_kernel

  // Init (3 memsets)
  hipMemsetAsync(hAll, 0, sizeof(float) * (size_t)Hh * Bb, stream);   // h_{-1} = 0
  hipMemsetAsync(cur_all, 0, 4 * (size_t)(Hh + Hh + Oo), stream);
  hipMemsetAsync(w + ent_off0, 0, ent_bytes, stream);                 // zero pad slots

  // x -> (I,T,B)
  transpose_x_kernel<<<(Tt / 2) * (Ii / 64), 256, 0, stream>>>(x, x2);

  // CSR build (all three pair-padded for int4 loads)
  hist3_kernel<<<1024, 256, 0, stream>>>(ih_rows, nnz_ih, ih_cur,
                                         hh_rows, nnz_hh, hh_cur,
                                         ho_rows, nnz_ho, ho_cur);
  scan3_kernel<<<3, 1024, 0, stream>>>(ih_cur, Hh, ih_rs, 1,
                                       hh_cur, Hh, hh_rs, 1,
                                       ho_cur, Oo, ho_rs, 1);
  scatter3_kernel<<<1024, 256, 0, stream>>>(
      ih_rows, ih_cols, ih_vals, nnz_ih, ih_cur, ih_ent,
      hh_rows, hh_cols, hh_vals, nnz_hh, hh_cur, hh_ent,
      ho_rows, ho_cols, ho_vals, nnz_ho, ho_cur, ho_ent);

  // pre[t][r][b] for all t, time-chunked (NCH chunks x Hh rows, wave each)
  preih_kernel<<<NCH * Hh / 4, 256, 0, stream>>>(
      ih_rs, ih_cur, (const int4*)ih_ent, hh_bias, x2, preAll);

  // Recurrence: one dispatch per step
  for (int t = 0; t < Tt; t++) {
    step_kernel<<<Hh / 4, 256, 0, stream>>>(
        hh_rs, hh_cur, (const int4*)hh_ent,
        preAll + (size_t)t * Hh * Bb,
        hAll + (size_t)t * Hh * Bb,
        hAll + (size_t)(t + 1) * Hh * Bb);
  }

  // Output spmm (XCD t-partitioned) + final transpose
  out_kernel<<<2048, 256, 0, stream>>>(
      ho_rs, ho_cur, (const int4*)ho_ent, ho_bias, hAll, out_tmp);
  transpose_out_kernel<<<Tt * (Oo / 64), 256, 0, stream>>>(out_tmp, out);

  (void)n_in; (void)out_size; (void)ws_size;
}